// Round 6
// baseline (9567.593 us; speedup 1.0000x reference)
//
#include <hip/hip_runtime.h>
#include <math.h>

#define BB 2048
#define TT 64
#define MM 256

typedef __attribute__((ext_vector_type(8))) unsigned short u16x8;

__device__ __forceinline__ float bf2f(unsigned short u) {
    union { unsigned int i; float f; } v; v.i = ((unsigned int)u) << 16; return v.f;
}
__device__ __forceinline__ unsigned short f2bf(float f) {
    union { float f; unsigned int i; } v; v.f = f;
    const unsigned int r = v.i + 0x7fff + ((v.i >> 16) & 1);  // RNE
    return (unsigned short)(r >> 16);
}

#if __has_builtin(__builtin_amdgcn_exp2f)
#define EXP2F(x) __builtin_amdgcn_exp2f(x)
#else
#define EXP2F(x) __expf((x) * 0.6931471805599453f)
#endif
#if __has_builtin(__builtin_amdgcn_rcpf)
#define RCPF(x) __builtin_amdgcn_rcpf(x)
#else
#define RCPF(x) (1.0f / (x))
#endif

#define TSC 2.885390081777927f  /* 2*log2(e): exp2(TSC*x) = e^(2x) */

// ---------------------------------------------------------------------------
// Tiled GEMM, bf16 output: Ue = enc @ U_d^T
// ---------------------------------------------------------------------------
__global__ __launch_bounds__(256) void gemm64_bf(
    const float* __restrict__ A, int lda,
    const float* __restrict__ W, int ldw,
    unsigned short* __restrict__ C, int ldc, int K)
{
    __shared__ float As[64][36];
    __shared__ float Ws[64][36];

    const int tid = threadIdx.x;
    const int row0 = blockIdx.x * 64;
    const int col0 = blockIdx.y * 64;

    const int lr = tid >> 3;
    const int lc4 = (tid & 7) * 4;
    const int tx = tid & 15;
    const int ty = tid >> 4;

    float acc[4][4] = {{0.f}};

    for (int k0 = 0; k0 < K; k0 += 32) {
        const float4 a0 = *(const float4*)&A[(size_t)(row0 + lr) * lda + k0 + lc4];
        const float4 a1 = *(const float4*)&A[(size_t)(row0 + lr + 32) * lda + k0 + lc4];
        const float4 w0 = *(const float4*)&W[(size_t)(col0 + lr) * ldw + k0 + lc4];
        const float4 w1 = *(const float4*)&W[(size_t)(col0 + lr + 32) * ldw + k0 + lc4];
        *(float4*)&As[lr][lc4] = a0;
        *(float4*)&As[lr + 32][lc4] = a1;
        *(float4*)&Ws[lr][lc4] = w0;
        *(float4*)&Ws[lr + 32][lc4] = w1;
        __syncthreads();

        #pragma unroll
        for (int kk = 0; kk < 32; kk += 4) {
            float4 a[4], w[4];
            #pragma unroll
            for (int i = 0; i < 4; i++) a[i] = *(const float4*)&As[ty + 16 * i][kk];
            #pragma unroll
            for (int j = 0; j < 4; j++) w[j] = *(const float4*)&Ws[tx + 16 * j][kk];
            #pragma unroll
            for (int i = 0; i < 4; i++)
                #pragma unroll
                for (int j = 0; j < 4; j++) {
                    acc[i][j] += a[i].x * w[j].x;
                    acc[i][j] += a[i].y * w[j].y;
                    acc[i][j] += a[i].z * w[j].z;
                    acc[i][j] += a[i].w * w[j].w;
                }
        }
        __syncthreads();
    }

    #pragma unroll
    for (int i = 0; i < 4; i++) {
        const int rr = row0 + ty + 16 * i;
        #pragma unroll
        for (int j = 0; j < 4; j++)
            C[(size_t)rr * ldc + col0 + tx + 16 * j] = f2bf(acc[i][j]);
    }
}

// ---------------------------------------------------------------------------
// q[row] = sum_m w_t_w[m] * enc[row][m]
// ---------------------------------------------------------------------------
__global__ __launch_bounds__(512) void compute_q(
    const float* __restrict__ enc, const float* __restrict__ w_t_w,
    float* __restrict__ q)
{
    const int row = blockIdx.x * 8 + (threadIdx.x >> 6);
    const int lane = threadIdx.x & 63;
    const float4 e = *(const float4*)&enc[(size_t)row * MM + lane * 4];
    const float4 w = *(const float4*)&w_t_w[lane * 4];
    float s = e.x * w.x + e.y * w.y + e.z * w.z + e.w * w.w;
    #pragma unroll
    for (int off = 32; off > 0; off >>= 1) s += __shfl_down(s, off);
    if (lane == 0) q[row] = s;
}

// ---------------------------------------------------------------------------
// Persistent fused decoder: 256 blocks x 1024 threads (16 waves/CU), block
// owns 8 batch rows. Phase A: 2 waves per row (128 m per lane). C-phase:
// every thread owns one gate column; waves 0-3 additionally own x1 columns.
// ---------------------------------------------------------------------------
__global__ __launch_bounds__(1024, 4) void fused_decoder(
    const unsigned short* __restrict__ Ue,   // [B][T][M] bf16
    const float* __restrict__ enc,           // [B][T][M] fp32
    const float* __restrict__ y,             // [B][T]
    const float* __restrict__ q,             // [B][T] precomputed w~.enc
    const float* __restrict__ W_d_w, const float* __restrict__ W_d_b,
    const float* __restrict__ v_d,
    const float* __restrict__ w_t_w, const float* __restrict__ w_t_b,
    const float* __restrict__ W_ih, const float* __restrict__ W_hh,
    const float* __restrict__ b_ih, const float* __restrict__ b_hh,
    const float* __restrict__ W_y_w, const float* __restrict__ W_y_b,
    const float* __restrict__ v_y_w, const float* __restrict__ v_y_b,
    float* __restrict__ out)                 // [2048 y_Tp1 | 2048*64 beta]
{
    const int tid = threadIdx.x;
    const int b0 = blockIdx.x * 8;
    const int wv = tid >> 6;        // 0..15
    const int lane = tid & 63;
    const int r_a = wv >> 1;        // phase-A row 0..7
    const int mh  = wv & 1;         // phase-A m-half
    const int t_a = lane;           // phase-A t'

    __shared__ __align__(16) float hc[8][512];       // h | c
    __shared__ float gates[8][1024];                 // h @ W_hh^T
    __shared__ __align__(16) float2 xv[8][256];      // (x1*TSC, v_d)
    __shared__ float lpart[8][2][64];
    __shared__ float betas[8][64];
    __shared__ float ytl[8];
    __shared__ __align__(16) float ctx[8][256];
    __shared__ float wihs[1024];
    __shared__ float bsums[1024];
    __shared__ float red[4][8];
    __shared__ float vsum_s;

    // ---- init ----
    float vdn = 0.f, bd = 0.f;
    if (tid < 256) {
        vdn = v_d[tid];
        bd = W_d_b[tid];
        #pragma unroll
        for (int r = 0; r < 8; r++)
            xv[r][tid] = make_float2(bd * TSC, vdn);   // x1(0) = b_d
    }
    wihs[tid & 1023] = W_ih[tid & 1023];
    bsums[tid & 1023] = b_ih[tid & 1023] + b_hh[tid & 1023];
    #pragma unroll
    for (int i = 0; i < 8; i++) ((float*)gates)[tid + i * 1024] = 0.f;
    #pragma unroll
    for (int i = 0; i < 4; i++) ((float*)hc)[tid + i * 1024] = 0.f;

    if (tid < 64) {
        float s = v_d[tid] + v_d[tid + 64] + v_d[tid + 128] + v_d[tid + 192];
        #pragma unroll
        for (int off = 32; off > 0; off >>= 1) s += __shfl_down(s, off);
        if (tid == 0) vsum_s = s;
    }

    const float qreg = q[(size_t)(b0 + r_a) * TT + t_a];
    const float yreg = y[(size_t)(b0 + r_a) * TT + t_a];
    const float wty = w_t_w[256];
    const float wtb = w_t_b[0];

    __syncthreads();
    const float VS = vsum_s;

    // per-lane Ue pointer: row (b0+r_a, t_a), half mh -> 16 u16x8 chunks
    const u16x8* __restrict__ uptr =
        (const u16x8*)(Ue + ((size_t)(b0 + r_a) * TT + t_a) * MM + mh * 128);
    const int mbase = mh * 128;

    for (int t = 0; t < TT; t++) {
        // ---- phase A: partial score over 128 m per lane ----
        float acc = 0.f;
        {
            u16x8 u0 = uptr[0], u1 = uptr[1], u2 = uptr[2], u3 = uptr[3];
            #pragma unroll
            for (int blk = 0; blk < 4; blk++) {
                u16x8 n0, n1, n2, n3;
                if (blk < 3) {
                    n0 = uptr[blk * 4 + 4]; n1 = uptr[blk * 4 + 5];
                    n2 = uptr[blk * 4 + 6]; n3 = uptr[blk * 4 + 7];
                }
                const int mb = mbase + blk * 32;
                #define PROC8(uu, mm)                                              \
                    _Pragma("unroll")                                              \
                    for (int j = 0; j < 8; j += 2) {                               \
                        const float4 x2 = *(const float4*)&xv[r_a][(mm) + j];      \
                        const float a0 = fmaf(bf2f(uu[j]),     TSC, x2.x);         \
                        const float a1 = fmaf(bf2f(uu[j + 1]), TSC, x2.z);         \
                        acc = fmaf(x2.y, RCPF(EXP2F(a0) + 1.f), acc);              \
                        acc = fmaf(x2.w, RCPF(EXP2F(a1) + 1.f), acc);              \
                    }
                PROC8(u0, mb)
                PROC8(u1, mb + 8)
                PROC8(u2, mb + 16)
                PROC8(u3, mb + 24)
                #undef PROC8
                u0 = n0; u1 = n1; u2 = n2; u3 = n3;
            }
        }
        lpart[r_a][mh][t_a] = acc;
        __syncthreads();

        // ---- combine halves + softmax (both waves of a row redundantly) ----
        const float l = VS - 2.f * (lpart[r_a][0][t_a] + lpart[r_a][1][t_a]);
        float mx = l;
        #pragma unroll
        for (int off = 32; off > 0; off >>= 1) mx = fmaxf(mx, __shfl_xor(mx, off));
        const float e = __expf(l - mx);
        float sm = e;
        #pragma unroll
        for (int off = 32; off > 0; off >>= 1) sm += __shfl_xor(sm, off);
        const float bta = e * RCPF(sm);

        if (mh == 0) {
            if (t == TT - 1) {
                betas[r_a][t_a] = bta;
                out[BB + (size_t)(b0 + r_a) * TT + t_a] = bta;
            }
            // ---- phase B: y_tilda ----
            float part = bta * qreg;
            if (t_a == t) part += fmaf(wty, yreg, wtb);
            #pragma unroll
            for (int off = 32; off > 0; off >>= 1) part += __shfl_down(part, off);
            if (t_a == 0) ytl[r_a] = part;
        }
        __syncthreads();

        // ---- phase C1: LSTM elementwise update (2 rows per thread) ----
        {
            const int p = tid & 255;
            const int rb2 = (tid >> 8) * 2;
            #pragma unroll
            for (int j = 0; j < 2; j++) {
                const int r = rb2 + j;
                const float x = ytl[r];
                const float gi = gates[r][p]       + x * wihs[p]       + bsums[p];
                const float gf = gates[r][p + 256] + x * wihs[p + 256] + bsums[p + 256];
                const float gg = gates[r][p + 512] + x * wihs[p + 512] + bsums[p + 512];
                const float go = gates[r][p + 768] + x * wihs[p + 768] + bsums[p + 768];
                const float c_old = hc[r][256 + p];
                const float si = RCPF(1.f + __expf(-gi));
                const float sf = RCPF(1.f + __expf(-gf));
                const float so = RCPF(1.f + __expf(-go));
                const float eg = __expf(2.f * gg);
                const float tg = 1.f - 2.f * RCPF(eg + 1.f);
                const float cn = sf * c_old + si * tg;
                const float ec = __expf(2.f * cn);
                const float tc = 1.f - 2.f * RCPF(ec + 1.f);
                hc[r][p] = so * tc;
                hc[r][256 + p] = cn;
            }
        }
        __syncthreads();

        // ---- phase C2: next x1 + gates (skip at last step) ----
        if (t < TT - 1) {
            // every thread: gate column tid (8 rows, K=256)
            {
                const int g = tid;
                const float* __restrict__ wg = W_hh + (size_t)g * 256;
                float ag[8] = {0.f, 0.f, 0.f, 0.f, 0.f, 0.f, 0.f, 0.f};
                float4 w3 = *(const float4*)(wg);
                for (int k = 0; k < 256; k += 4) {
                    float4 nw3;
                    if (k < 252) nw3 = *(const float4*)(wg + k + 4);
                    #pragma unroll
                    for (int r = 0; r < 8; r++) {
                        const float4 h4 = *(const float4*)&hc[r][k];
                        ag[r] += w3.x * h4.x + w3.y * h4.y + w3.z * h4.z + w3.w * h4.w;
                    }
                    w3 = nw3;
                }
                #pragma unroll
                for (int r = 0; r < 8; r++) gates[r][g] = ag[r];
            }
            // waves 0-3 additionally: x1 column tid (8 rows, K=512)
            if (tid < 256) {
                const int n = tid;
                const float* __restrict__ wr = W_d_w + (size_t)n * 512;
                float ax[8] = {0.f, 0.f, 0.f, 0.f, 0.f, 0.f, 0.f, 0.f};
                float4 w1 = *(const float4*)(wr);
                float4 w2 = *(const float4*)(wr + 256);
                for (int k = 0; k < 256; k += 4) {
                    float4 nw1, nw2;
                    if (k < 252) {
                        nw1 = *(const float4*)(wr + k + 4);
                        nw2 = *(const float4*)(wr + 256 + k + 4);
                    }
                    #pragma unroll
                    for (int r = 0; r < 8; r++) {
                        const float4 h4 = *(const float4*)&hc[r][k];
                        const float4 c4 = *(const float4*)&hc[r][256 + k];
                        ax[r] += w1.x * h4.x + w1.y * h4.y + w1.z * h4.z + w1.w * h4.w
                               + w2.x * c4.x + w2.y * c4.y + w2.z * c4.z + w2.w * c4.w;
                    }
                    w1 = nw1; w2 = nw2;
                }
                #pragma unroll
                for (int r = 0; r < 8; r++)
                    xv[r][n] = make_float2((ax[r] + bd) * TSC, vdn);
            }
        }
        __syncthreads();
    }

    // ---- ctx = beta(63) @ enc slice (fp32): thread owns (row, 2 m) ----
    {
        const int r = tid >> 7;
        const int m0 = (tid & 127) * 2;
        const float* __restrict__ ep = enc + (size_t)(b0 + r) * TT * MM + m0;
        float c0 = 0.f, c1 = 0.f;
        #pragma unroll 8
        for (int tt2 = 0; tt2 < TT; tt2++) {
            const float2 e2 = *(const float2*)(ep + (size_t)tt2 * MM);
            const float bta = betas[r][tt2];
            c0 = fmaf(bta, e2.x, c0);
            c1 = fmaf(bta, e2.y, c1);
        }
        ctx[r][m0] = c0;
        ctx[r][m0 + 1] = c1;
    }
    __syncthreads();

    // ---- final head ----
    if (tid < 256) {
        const int n = tid;
        const float* __restrict__ wr = W_y_w + (size_t)n * 512;
        float acc[8] = {0.f, 0.f, 0.f, 0.f, 0.f, 0.f, 0.f, 0.f};
        #pragma unroll 2
        for (int k = 0; k < 256; k += 4) {
            const float4 wh = *(const float4*)(wr + k);
            const float4 wc = *(const float4*)(wr + 256 + k);
            #pragma unroll
            for (int r = 0; r < 8; r++) {
                const float4 h4 = *(const float4*)&hc[r][k];
                const float4 c4 = *(const float4*)&ctx[r][k];
                acc[r] += wh.x * h4.x + wh.y * h4.y + wh.z * h4.z + wh.w * h4.w
                        + wc.x * c4.x + wc.y * c4.y + wc.z * c4.z + wc.w * c4.w;
            }
        }
        const float vy = v_y_w[n];
        const float by = W_y_b[n];
        const int wv4 = tid >> 6;
        const int ln = tid & 63;
        #pragma unroll
        for (int r = 0; r < 8; r++) {
            float v = (acc[r] + by) * vy;
            #pragma unroll
            for (int off = 32; off > 0; off >>= 1) v += __shfl_down(v, off);
            if (ln == 0) red[wv4][r] = v;
        }
    }
    __syncthreads();
    if (tid < 8)
        out[b0 + tid] = red[0][tid] + red[1][tid] + red[2][tid] + red[3][tid] + v_y_b[0];
}

// ---------------------------------------------------------------------------
extern "C" void kernel_launch(void* const* d_in, const int* in_sizes, int n_in,
                              void* d_out, int out_size, void* d_ws, size_t ws_size,
                              hipStream_t stream)
{
    const float* enc      = (const float*)d_in[0];
    const float* y        = (const float*)d_in[1];
    const float* W_d_w    = (const float*)d_in[2];
    const float* W_d_b    = (const float*)d_in[3];
    const float* U_d_w    = (const float*)d_in[4];
    const float* v_d_w    = (const float*)d_in[5];
    const float* w_tilda_w= (const float*)d_in[6];
    const float* w_tilda_b= (const float*)d_in[7];
    const float* W_y_w    = (const float*)d_in[8];
    const float* W_y_b    = (const float*)d_in[9];
    const float* v_y_w    = (const float*)d_in[10];
    const float* v_y_b    = (const float*)d_in[11];
    const float* W_ih     = (const float*)d_in[12];
    const float* W_hh     = (const float*)d_in[13];
    const float* b_ih     = (const float*)d_in[14];
    const float* b_hh     = (const float*)d_in[15];

    float* out = (float*)d_out;

    unsigned short* Ue_bf = (unsigned short*)d_ws;            // 33.5M bf16
    float* qbuf = (float*)(Ue_bf + (size_t)BB * TT * MM);     // 131072 fp32

    // Ue = enc @ U_d^T, stored bf16
    gemm64_bf<<<dim3(BB * TT / 64, MM / 64), 256, 0, stream>>>(
        enc, MM, U_d_w, MM, Ue_bf, MM, MM);

    // q = enc . w_tilda (step-invariant part of y_tilda)
    compute_q<<<BB * TT / 8, 512, 0, stream>>>(enc, w_tilda_w, qbuf);

    // the whole 64-step recurrence + final head
    fused_decoder<<<BB / 8, 1024, 0, stream>>>(
        Ue_bf, enc, y, qbuf, W_d_w, W_d_b, v_d_w, w_tilda_w, w_tilda_b,
        W_ih, W_hh, b_ih, b_hh, W_y_w, W_y_b, v_y_w, v_y_b, out);
}

// Round 7
// 6950.424 us; speedup vs baseline: 1.3765x; 1.3765x over previous
//
#include <hip/hip_runtime.h>
#include <math.h>

#define BB 2048
#define TT 64
#define MM 256

typedef __attribute__((ext_vector_type(8))) unsigned short u16x8;
typedef _Float16 f16x2 __attribute__((ext_vector_type(2)));
typedef _Float16 f16x8 __attribute__((ext_vector_type(8)));

union U8 { f16x8 v; f16x2 p[4]; };

__device__ __forceinline__ float bf2f(unsigned short u) {
    union { unsigned int i; float f; } v; v.i = ((unsigned int)u) << 16; return v.f;
}
__device__ __forceinline__ unsigned short f2bf(float f) {
    union { float f; unsigned int i; } v; v.f = f;
    const unsigned int r = v.i + 0x7fff + ((v.i >> 16) & 1);  // RNE
    return (unsigned short)(r >> 16);
}

#if __has_builtin(__builtin_amdgcn_fdot2)
#define FDOT2(a, b, c) __builtin_amdgcn_fdot2((a), (b), (c), false)
#else
__device__ __forceinline__ float FDOT2(f16x2 a, f16x2 b, float c) {
    return c + (float)a[0] * (float)b[0] + (float)a[1] * (float)b[1];
}
#endif

#if __has_builtin(__builtin_amdgcn_exp2f)
#define EXP2F(x) __builtin_amdgcn_exp2f(x)
#else
#define EXP2F(x) __expf((x) * 0.6931471805599453f)
#endif
#if __has_builtin(__builtin_amdgcn_rcpf)
#define RCPF(x) __builtin_amdgcn_rcpf(x)
#else
#define RCPF(x) (1.0f / (x))
#endif

#define TSC 2.885390081777927f  /* 2*log2(e): exp2(TSC*x) = e^(2x) */

// ---------------------------------------------------------------------------
// Tiled GEMM, bf16 output: Ue = enc @ U_d^T
// ---------------------------------------------------------------------------
__global__ __launch_bounds__(256) void gemm64_bf(
    const float* __restrict__ A, int lda,
    const float* __restrict__ W, int ldw,
    unsigned short* __restrict__ C, int ldc, int K)
{
    __shared__ float As[64][36];
    __shared__ float Ws[64][36];

    const int tid = threadIdx.x;
    const int row0 = blockIdx.x * 64;
    const int col0 = blockIdx.y * 64;

    const int lr = tid >> 3;
    const int lc4 = (tid & 7) * 4;
    const int tx = tid & 15;
    const int ty = tid >> 4;

    float acc[4][4] = {{0.f}};

    for (int k0 = 0; k0 < K; k0 += 32) {
        const float4 a0 = *(const float4*)&A[(size_t)(row0 + lr) * lda + k0 + lc4];
        const float4 a1 = *(const float4*)&A[(size_t)(row0 + lr + 32) * lda + k0 + lc4];
        const float4 w0 = *(const float4*)&W[(size_t)(col0 + lr) * ldw + k0 + lc4];
        const float4 w1 = *(const float4*)&W[(size_t)(col0 + lr + 32) * ldw + k0 + lc4];
        *(float4*)&As[lr][lc4] = a0;
        *(float4*)&As[lr + 32][lc4] = a1;
        *(float4*)&Ws[lr][lc4] = w0;
        *(float4*)&Ws[lr + 32][lc4] = w1;
        __syncthreads();

        #pragma unroll
        for (int kk = 0; kk < 32; kk += 4) {
            float4 a[4], w[4];
            #pragma unroll
            for (int i = 0; i < 4; i++) a[i] = *(const float4*)&As[ty + 16 * i][kk];
            #pragma unroll
            for (int j = 0; j < 4; j++) w[j] = *(const float4*)&Ws[tx + 16 * j][kk];
            #pragma unroll
            for (int i = 0; i < 4; i++)
                #pragma unroll
                for (int j = 0; j < 4; j++) {
                    acc[i][j] += a[i].x * w[j].x;
                    acc[i][j] += a[i].y * w[j].y;
                    acc[i][j] += a[i].z * w[j].z;
                    acc[i][j] += a[i].w * w[j].w;
                }
        }
        __syncthreads();
    }

    #pragma unroll
    for (int i = 0; i < 4; i++) {
        const int rr = row0 + ty + 16 * i;
        #pragma unroll
        for (int j = 0; j < 4; j++)
            C[(size_t)rr * ldc + col0 + tx + 16 * j] = f2bf(acc[i][j]);
    }
}

// ---------------------------------------------------------------------------
// q[row] = sum_m w_t_w[m] * enc[row][m]
// ---------------------------------------------------------------------------
__global__ __launch_bounds__(512) void compute_q(
    const float* __restrict__ enc, const float* __restrict__ w_t_w,
    float* __restrict__ q)
{
    const int row = blockIdx.x * 8 + (threadIdx.x >> 6);
    const int lane = threadIdx.x & 63;
    const float4 e = *(const float4*)&enc[(size_t)row * MM + lane * 4];
    const float4 w = *(const float4*)&w_t_w[lane * 4];
    float s = e.x * w.x + e.y * w.y + e.z * w.z + e.w * w.w;
    #pragma unroll
    for (int off = 32; off > 0; off >>= 1) s += __shfl_down(s, off);
    if (lane == 0) q[row] = s;
}

// ---------------------------------------------------------------------------
// fp32 -> f16 weight convert
// ---------------------------------------------------------------------------
__global__ __launch_bounds__(256) void cvt_f16(
    const float* __restrict__ in, _Float16* __restrict__ out, int n)
{
    int i = blockIdx.x * 256 + threadIdx.x;
    const int stride = gridDim.x * 256;
    for (; i < n; i += stride) out[i] = (_Float16)in[i];
}

// ---------------------------------------------------------------------------
// Persistent fused decoder: 512 blocks x 512 threads (2 blocks/CU, 16 w/CU),
// block owns 4 batch rows. Phase A: 2 waves/row, 128 m per lane, bf16 Ue.
// Phase C: f16 weights + v_dot2_f32_f16; h/c staged f16 in LDS, c fp32.
// ---------------------------------------------------------------------------
__global__ __launch_bounds__(512, 4) void fused_decoder(
    const unsigned short* __restrict__ Ue,   // [B][T][M] bf16
    const float* __restrict__ enc,           // [B][T][M] fp32
    const float* __restrict__ y,             // [B][T]
    const float* __restrict__ q,             // [B][T] precomputed w~.enc
    const _Float16* __restrict__ Wd_h,       // [256][512] f16
    const float* __restrict__ W_d_b,
    const float* __restrict__ v_d,
    const float* __restrict__ w_t_w, const float* __restrict__ w_t_b,
    const float* __restrict__ W_ih,
    const _Float16* __restrict__ Whh_h,      // [1024][256] f16
    const float* __restrict__ b_ih, const float* __restrict__ b_hh,
    const float* __restrict__ W_y_w, const float* __restrict__ W_y_b,
    const float* __restrict__ v_y_w, const float* __restrict__ v_y_b,
    float* __restrict__ out)                 // [2048 y_Tp1 | 2048*64 beta]
{
    const int tid = threadIdx.x;
    const int b0 = blockIdx.x * 4;
    const int wv = tid >> 6;        // 0..7
    const int lane = tid & 63;
    const int r_a = wv >> 1;        // phase-A row 0..3
    const int mh  = wv & 1;         // phase-A m-half
    const int t_a = lane;

    __shared__ __align__(16) _Float16 hcH[4][512];   // h(0..255) | c(256..511)
    __shared__ __align__(16) float cc[4][256];       // c fp32 (recurrent state)
    __shared__ __align__(16) _Float16 gatesH[4][1024];
    __shared__ __align__(16) float2 xv[4][256];      // (x1*TSC, v_d)
    __shared__ float lpart[4][2][64];
    __shared__ float betas[4][64];
    __shared__ float ytl[4];
    __shared__ __align__(16) float ctx[4][256];
    __shared__ float wihs[1024];
    __shared__ float bsums[1024];
    __shared__ float red[4][4];
    __shared__ float vsum_s;

    // ---- init ----
    float vdn = 0.f, bd = 0.f;
    if (tid < 256) {
        vdn = v_d[tid];
        bd = W_d_b[tid];
        #pragma unroll
        for (int r = 0; r < 4; r++) {
            xv[r][tid] = make_float2(bd * TSC, vdn);   // x1(0) = b_d
            cc[r][tid] = 0.f;
        }
    }
    for (int i = tid; i < 1024; i += 512) {
        wihs[i] = W_ih[i];
        bsums[i] = b_ih[i] + b_hh[i];
    }
    for (int i = tid; i < 2048; i += 512) ((unsigned int*)gatesH)[i] = 0u;
    for (int i = tid; i < 1024; i += 512) ((unsigned int*)hcH)[i] = 0u;

    if (tid < 64) {
        float s = v_d[tid] + v_d[tid + 64] + v_d[tid + 128] + v_d[tid + 192];
        #pragma unroll
        for (int off = 32; off > 0; off >>= 1) s += __shfl_down(s, off);
        if (tid == 0) vsum_s = s;
    }

    const float qreg = q[(size_t)(b0 + r_a) * TT + t_a];
    const float yreg = y[(size_t)(b0 + r_a) * TT + t_a];
    const float wty = w_t_w[256];
    const float wtb = w_t_b[0];

    __syncthreads();
    const float VS = vsum_s;

    const u16x8* __restrict__ uptr =
        (const u16x8*)(Ue + ((size_t)(b0 + r_a) * TT + t_a) * MM + mh * 128);
    const int mbase = mh * 128;

    for (int t = 0; t < TT; t++) {
        // ---- phase A: partial score over 128 m per lane ----
        float acc = 0.f;
        {
            u16x8 u0 = uptr[0], u1 = uptr[1], u2 = uptr[2], u3 = uptr[3];
            #pragma unroll
            for (int blk = 0; blk < 4; blk++) {
                u16x8 n0, n1, n2, n3;
                if (blk < 3) {
                    n0 = uptr[blk * 4 + 4]; n1 = uptr[blk * 4 + 5];
                    n2 = uptr[blk * 4 + 6]; n3 = uptr[blk * 4 + 7];
                }
                const int mb = mbase + blk * 32;
                #define PROC8(uu, mm)                                              \
                    _Pragma("unroll")                                              \
                    for (int j = 0; j < 8; j += 2) {                               \
                        const float4 x2 = *(const float4*)&xv[r_a][(mm) + j];      \
                        const float a0 = fmaf(bf2f(uu[j]),     TSC, x2.x);         \
                        const float a1 = fmaf(bf2f(uu[j + 1]), TSC, x2.z);         \
                        acc = fmaf(x2.y, RCPF(EXP2F(a0) + 1.f), acc);              \
                        acc = fmaf(x2.w, RCPF(EXP2F(a1) + 1.f), acc);              \
                    }
                PROC8(u0, mb)
                PROC8(u1, mb + 8)
                PROC8(u2, mb + 16)
                PROC8(u3, mb + 24)
                #undef PROC8
                u0 = n0; u1 = n1; u2 = n2; u3 = n3;
            }
        }
        lpart[r_a][mh][t_a] = acc;
        __syncthreads();

        // ---- combine + softmax (both waves of a row, redundant) ----
        const float l = VS - 2.f * (lpart[r_a][0][t_a] + lpart[r_a][1][t_a]);
        float mx = l;
        #pragma unroll
        for (int off = 32; off > 0; off >>= 1) mx = fmaxf(mx, __shfl_xor(mx, off));
        const float e = __expf(l - mx);
        float sm = e;
        #pragma unroll
        for (int off = 32; off > 0; off >>= 1) sm += __shfl_xor(sm, off);
        const float bta = e * RCPF(sm);

        if (mh == 0) {
            if (t == TT - 1) {
                betas[r_a][t_a] = bta;
                out[BB + (size_t)(b0 + r_a) * TT + t_a] = bta;
            }
            // ---- phase B: y_tilda ----
            float part = bta * qreg;
            if (t_a == t) part += fmaf(wty, yreg, wtb);
            #pragma unroll
            for (int off = 32; off > 0; off >>= 1) part += __shfl_down(part, off);
            if (t_a == 0) ytl[r_a] = part;
        }
        __syncthreads();

        // ---- phase C1: LSTM elementwise update (2 rows per thread) ----
        {
            const int p = tid & 255;
            const int rb2 = (tid >> 8) * 2;
            #pragma unroll
            for (int j = 0; j < 2; j++) {
                const int r = rb2 + j;
                const float x = ytl[r];
                const float gi = (float)gatesH[r][p]       + x * wihs[p]       + bsums[p];
                const float gf = (float)gatesH[r][p + 256] + x * wihs[p + 256] + bsums[p + 256];
                const float gg = (float)gatesH[r][p + 512] + x * wihs[p + 512] + bsums[p + 512];
                const float go = (float)gatesH[r][p + 768] + x * wihs[p + 768] + bsums[p + 768];
                const float c_old = cc[r][p];
                const float si = RCPF(1.f + __expf(-gi));
                const float sf = RCPF(1.f + __expf(-gf));
                const float so = RCPF(1.f + __expf(-go));
                const float eg = __expf(2.f * gg);
                const float tg = 1.f - 2.f * RCPF(eg + 1.f);
                const float cn = sf * c_old + si * tg;
                const float ec = __expf(2.f * cn);
                const float tc = 1.f - 2.f * RCPF(ec + 1.f);
                cc[r][p] = cn;
                hcH[r][p] = (_Float16)(so * tc);
                hcH[r][256 + p] = (_Float16)cn;
            }
        }
        __syncthreads();

        // ---- phase C2: next x1 + gates via f16 dot2 (skip at last step) ----
        if (t < TT - 1) {
            if (tid < 256) {
                // x1 col n (K=512) + gate col n (K=256): 1536 dot2
                const int n = tid;
                const _Float16* __restrict__ wr = Wd_h + (size_t)n * 512;
                const _Float16* __restrict__ wg = Whh_h + (size_t)n * 256;
                float ax[4] = {0.f, 0.f, 0.f, 0.f};
                float ag[4] = {0.f, 0.f, 0.f, 0.f};
                U8 wx0, wx1, wg0, wg1;
                wx0.v = *(const f16x8*)(wr);
                wg0.v = *(const f16x8*)(wg);
                wx1.v = *(const f16x8*)(wr + 8);
                wg1.v = *(const f16x8*)(wg + 8);
                for (int k8 = 0; k8 < 32; k8++) {
                    U8 cx = wx0, cg = wg0;
                    wx0 = wx1; wg0 = wg1;
                    if (k8 + 2 < 32) {
                        wx1.v = *(const f16x8*)(wr + (k8 + 2) * 8);
                        wg1.v = *(const f16x8*)(wg + (k8 + 2) * 8);
                    }
                    #pragma unroll
                    for (int r = 0; r < 4; r++) {
                        U8 h; h.v = *(const f16x8*)&hcH[r][k8 * 8];
                        #pragma unroll
                        for (int u = 0; u < 4; u++) {
                            ax[r] = FDOT2(h.p[u], cx.p[u], ax[r]);
                            ag[r] = FDOT2(h.p[u], cg.p[u], ag[r]);
                        }
                    }
                }
                // x1 c-part: k 256..511
                wx0.v = *(const f16x8*)(wr + 256);
                wx1.v = *(const f16x8*)(wr + 264);
                for (int k8 = 0; k8 < 32; k8++) {
                    U8 cx = wx0;
                    wx0 = wx1;
                    if (k8 + 2 < 32)
                        wx1.v = *(const f16x8*)(wr + 256 + (k8 + 2) * 8);
                    #pragma unroll
                    for (int r = 0; r < 4; r++) {
                        U8 h; h.v = *(const f16x8*)&hcH[r][256 + k8 * 8];
                        #pragma unroll
                        for (int u = 0; u < 4; u++)
                            ax[r] = FDOT2(h.p[u], cx.p[u], ax[r]);
                    }
                }
                #pragma unroll
                for (int r = 0; r < 4; r++) {
                    xv[r][n] = make_float2((ax[r] + bd) * TSC, vdn);
                    gatesH[r][n] = (_Float16)ag[r];
                }
            } else {
                // 3 gate cols (K=256 each): 1536 dot2
                const int n2 = tid - 256;
                const _Float16* __restrict__ wA = Whh_h + (size_t)(n2 + 256) * 256;
                const _Float16* __restrict__ wB = Whh_h + (size_t)(n2 + 512) * 256;
                const _Float16* __restrict__ wC = Whh_h + (size_t)(n2 + 768) * 256;
                float aA[4] = {0.f, 0.f, 0.f, 0.f};
                float aB[4] = {0.f, 0.f, 0.f, 0.f};
                float aC[4] = {0.f, 0.f, 0.f, 0.f};
                U8 a0, b0u, c0, a1, b1u, c1;
                a0.v = *(const f16x8*)(wA); b0u.v = *(const f16x8*)(wB); c0.v = *(const f16x8*)(wC);
                a1.v = *(const f16x8*)(wA + 8); b1u.v = *(const f16x8*)(wB + 8); c1.v = *(const f16x8*)(wC + 8);
                for (int k8 = 0; k8 < 32; k8++) {
                    U8 ca = a0, cb = b0u, ccu = c0;
                    a0 = a1; b0u = b1u; c0 = c1;
                    if (k8 + 2 < 32) {
                        a1.v = *(const f16x8*)(wA + (k8 + 2) * 8);
                        b1u.v = *(const f16x8*)(wB + (k8 + 2) * 8);
                        c1.v = *(const f16x8*)(wC + (k8 + 2) * 8);
                    }
                    #pragma unroll
                    for (int r = 0; r < 4; r++) {
                        U8 h; h.v = *(const f16x8*)&hcH[r][k8 * 8];
                        #pragma unroll
                        for (int u = 0; u < 4; u++) {
                            aA[r] = FDOT2(h.p[u], ca.p[u], aA[r]);
                            aB[r] = FDOT2(h.p[u], cb.p[u], aB[r]);
                            aC[r] = FDOT2(h.p[u], ccu.p[u], aC[r]);
                        }
                    }
                }
                #pragma unroll
                for (int r = 0; r < 4; r++) {
                    gatesH[r][n2 + 256] = (_Float16)aA[r];
                    gatesH[r][n2 + 512] = (_Float16)aB[r];
                    gatesH[r][n2 + 768] = (_Float16)aC[r];
                }
            }
        }
        __syncthreads();
    }

    // ---- ctx = beta(63) @ enc slice (fp32): thread owns (row, 2 m) ----
    {
        const int r = tid >> 7;
        const int m0 = (tid & 127) * 2;
        const float* __restrict__ ep = enc + (size_t)(b0 + r) * TT * MM + m0;
        float c0 = 0.f, c1 = 0.f;
        #pragma unroll 8
        for (int tt2 = 0; tt2 < TT; tt2++) {
            const float2 e2 = *(const float2*)(ep + (size_t)tt2 * MM);
            const float bta = betas[r][tt2];
            c0 = fmaf(bta, e2.x, c0);
            c1 = fmaf(bta, e2.y, c1);
        }
        ctx[r][m0] = c0;
        ctx[r][m0 + 1] = c1;
    }
    __syncthreads();

    // ---- final head ----
    if (tid < 256) {
        const int n = tid;
        const float* __restrict__ wr = W_y_w + (size_t)n * 512;
        float acc[4] = {0.f, 0.f, 0.f, 0.f};
        for (int k = 0; k < 256; k += 4) {
            const float4 wh = *(const float4*)(wr + k);
            const float4 wc = *(const float4*)(wr + 256 + k);
            #pragma unroll
            for (int r = 0; r < 4; r++) {
                const float4 c4 = *(const float4*)&ctx[r][k];
                acc[r] += wh.x * (float)hcH[r][k]     + wh.y * (float)hcH[r][k + 1]
                        + wh.z * (float)hcH[r][k + 2] + wh.w * (float)hcH[r][k + 3]
                        + wc.x * c4.x + wc.y * c4.y + wc.z * c4.z + wc.w * c4.w;
            }
        }
        const float vy = v_y_w[n];
        const float by = W_y_b[n];
        const int wv4 = tid >> 6;
        const int ln = tid & 63;
        #pragma unroll
        for (int r = 0; r < 4; r++) {
            float v = (acc[r] + by) * vy;
            #pragma unroll
            for (int off = 32; off > 0; off >>= 1) v += __shfl_down(v, off);
            if (ln == 0) red[wv4][r] = v;
        }
    }
    __syncthreads();
    if (tid < 4)
        out[b0 + tid] = red[0][tid] + red[1][tid] + red[2][tid] + red[3][tid] + v_y_b[0];
}

// ---------------------------------------------------------------------------
extern "C" void kernel_launch(void* const* d_in, const int* in_sizes, int n_in,
                              void* d_out, int out_size, void* d_ws, size_t ws_size,
                              hipStream_t stream)
{
    const float* enc      = (const float*)d_in[0];
    const float* y        = (const float*)d_in[1];
    const float* W_d_w    = (const float*)d_in[2];
    const float* W_d_b    = (const float*)d_in[3];
    const float* U_d_w    = (const float*)d_in[4];
    const float* v_d_w    = (const float*)d_in[5];
    const float* w_tilda_w= (const float*)d_in[6];
    const float* w_tilda_b= (const float*)d_in[7];
    const float* W_y_w    = (const float*)d_in[8];
    const float* W_y_b    = (const float*)d_in[9];
    const float* v_y_w    = (const float*)d_in[10];
    const float* v_y_b    = (const float*)d_in[11];
    const float* W_ih     = (const float*)d_in[12];
    const float* W_hh     = (const float*)d_in[13];
    const float* b_ih     = (const float*)d_in[14];
    const float* b_hh     = (const float*)d_in[15];

    float* out = (float*)d_out;

    unsigned short* Ue_bf = (unsigned short*)d_ws;              // 33.5M u16
    float* qbuf = (float*)(Ue_bf + (size_t)BB * TT * MM);       // 131072 f32
    _Float16* Wd_h = (_Float16*)(qbuf + BB * TT);               // 131072 f16
    _Float16* Whh_h = Wd_h + 256 * 512;                         // 262144 f16

    // Ue = enc @ U_d^T, stored bf16
    gemm64_bf<<<dim3(BB * TT / 64, MM / 64), 256, 0, stream>>>(
        enc, MM, U_d_w, MM, Ue_bf, MM, MM);

    // q = enc . w_tilda (step-invariant part of y_tilda)
    compute_q<<<BB * TT / 8, 512, 0, stream>>>(enc, w_tilda_w, qbuf);

    // weights -> f16
    cvt_f16<<<128, 256, 0, stream>>>(W_d_w, Wd_h, 256 * 512);
    cvt_f16<<<128, 256, 0, stream>>>(W_hh, Whh_h, 1024 * 256);

    // the whole 64-step recurrence + final head
    fused_decoder<<<BB / 4, 512, 0, stream>>>(
        Ue_bf, enc, y, qbuf, Wd_h, W_d_b, v_d_w, w_tilda_w, w_tilda_b,
        W_ih, Whh_h, b_ih, b_hh, W_y_w, W_y_b, v_y_w, v_y_b, out);
}